// Round 5
// baseline (62.644 us; speedup 1.0000x reference)
//
#include <hip/hip_runtime.h>
#include <hip/hip_bf16.h>
#include <hip/hip_fp16.h>

// Problem constants (from reference)
#define IMG_H 512
#define IMG_W 512
#define N_VIEWS 180
#define N_DET 512
#define N_SAMPLES 512

#define N_RAYS (N_VIEWS * N_DET)          // 92160
#define IMG_N (IMG_H * IMG_W)             // 262144
#define IMG_BYTES (IMG_N * sizeof(float)) // 1 MiB

// fp16 packed-quad grids with a 2-ring zero pad, TWO layouts:
//  Qrm[(iy0+2)*QDIM + (ix0+2)] = half4{ v00=I[iy0][ix0],   v01=I[iy0][ix0+1],
//                                       v10=I[iy0+1][ix0], v11=I[iy0+1][ix0+1] }
//  Qcm[(ix0+2)*QDIM + (iy0+2)] = half4{ v00, v10, v01, v11 }   (transposed)
// for ix0,iy0 in [-2,512], I==0 outside [0,512)^2. Clamping the float coord
// to [-2,512] always lands on a quad that reproduces the reference's
// zero-outside gather exactly (all-zero quad when the clamp engages).
#define QDIM 515
#define Q_N (QDIM * QDIM)                 // 265225
#define Q_BYTES (Q_N * sizeof(uint2))     // ~2.1 MiB
#define QOFF (2 * QDIM + 2)

#define K_CHUNKS 4
#define N_WAVES (N_VIEWS * 8 * K_CHUNKS)  // 5760

// ---------------------------------------------------------------------------
// k1: out_relu = relu(x + reco)   (float4)
// ---------------------------------------------------------------------------
__global__ __launch_bounds__(256) void add_relu_kernel(
        const float4* __restrict__ x, const float4* __restrict__ r,
        float4* __restrict__ out_relu) {
    int i = blockIdx.x * blockDim.x + threadIdx.x;
    float4 a = x[i];
    float4 b = r[i];
    out_relu[i] = make_float4(fmaxf(a.x + b.x, 0.f), fmaxf(a.y + b.y, 0.f),
                              fmaxf(a.z + b.z, 0.f), fmaxf(a.w + b.w, 0.f));
}

// ---------------------------------------------------------------------------
// k2: pack BOTH fp16 quad layouts straight from x+reco (no upd buffer)
// ---------------------------------------------------------------------------
__global__ __launch_bounds__(256) void pack_dual_kernel(
        const float* __restrict__ x, const float* __restrict__ r,
        uint2* __restrict__ Qrm, uint2* __restrict__ Qcm) {
    int i = blockIdx.x * blockDim.x + threadIdx.x;
    if (i >= Q_N) return;
    int row = i / QDIM;
    int col = i - row * QDIM;
    int iy0 = row - 2, ix0 = col - 2;
    const bool y0v = (unsigned)iy0 < (unsigned)IMG_H;
    const bool y1v = (unsigned)(iy0 + 1) < (unsigned)IMG_H;
    const bool x0v = (unsigned)ix0 < (unsigned)IMG_W;
    const bool x1v = (unsigned)(ix0 + 1) < (unsigned)IMG_W;
    float v00 = 0.f, v01 = 0.f, v10 = 0.f, v11 = 0.f;
    if (y0v) {
        int base = iy0 * IMG_W;
        if (x0v) v00 = x[base + ix0] + r[base + ix0];
        if (x1v) v01 = x[base + ix0 + 1] + r[base + ix0 + 1];
    }
    if (y1v) {
        int base = (iy0 + 1) * IMG_W;
        if (x0v) v10 = x[base + ix0] + r[base + ix0];
        if (x1v) v11 = x[base + ix0 + 1] + r[base + ix0 + 1];
    }
    __half2 lo = __floats2half2_rn(v00, v01);
    __half2 hi = __floats2half2_rn(v10, v11);
    Qrm[i] = make_uint2(*reinterpret_cast<unsigned*>(&lo),
                        *reinterpret_cast<unsigned*>(&hi));
    __half2 lo2 = __floats2half2_rn(v00, v10);
    __half2 hi2 = __floats2half2_rn(v01, v11);
    Qcm[col * QDIM + row] = make_uint2(*reinterpret_cast<unsigned*>(&lo2),
                                       *reinterpret_cast<unsigned*>(&hi2));
}

// ---------------------------------------------------------------------------
// fp16 packed-quad bilinear sample: ONE 8B gather, zero masking needed.
// Qb is pre-offset by QOFF so indices in [-2,512] work directly.
// ---------------------------------------------------------------------------
__device__ __forceinline__ float sample_h(const uint2* __restrict__ Qb,
                                          float t, float dx, float dy,
                                          float bx, float by, float acc) {
    float px = fmaf(t, dx, bx);
    float py = fmaf(t, dy, by);
    px = __builtin_amdgcn_fmed3f(px, -2.0f, 512.0f);
    py = __builtin_amdgcn_fmed3f(py, -2.0f, 512.0f);
    const float ixf = floorf(px);
    const float iyf = floorf(py);
    const float fx = px - ixf;
    const float fy = py - iyf;
    const int ix = (int)ixf;
    const int iy = (int)iyf;

    const uint2 qw = Qb[iy * QDIM + ix];
    const __half2 ha = *reinterpret_cast<const __half2*>(&qw.x);
    const __half2 hb = *reinterpret_cast<const __half2*>(&qw.y);
    const float2 fa = __half22float2(ha);
    const float2 fb = __half22float2(hb);

    const float gx = 1.f - fx;
    const float gy = 1.f - fy;
    acc = fmaf(fa.x, gx * gy, acc);
    acc = fmaf(fa.y, fx * gy, acc);
    acc = fmaf(fb.x, gx * fy, acc);
    acc = fmaf(fb.y, fx * fy, acc);
    return acc;
}

// ---------------------------------------------------------------------------
// k3: fan-beam projection, arc-ordered. THREAD = (ray, sample-chunk).
//   wave = 64 consecutive dets of one view -> lanes at equal t form a
//   straight, compact, uniformly-spaced segment (great L1 locality).
//   Layout chosen per view so the segment runs along the fast axis.
//   Out-of-box samples read all-zero pad quads -> no per-lane bounds checks.
// ---------------------------------------------------------------------------
__global__ __launch_bounds__(256) void fanproj_arc_kernel(
        const uint2* __restrict__ Qrm, const uint2* __restrict__ Qcm,
        const float* __restrict__ src_pos,
        const float* __restrict__ det_center,
        const float* __restrict__ det_u,
        float* __restrict__ sino) {
    const int tid   = blockIdx.x * blockDim.x + threadIdx.x;
    const int wid   = tid >> 6;              // [0, 5760)
    const int lane  = tid & 63;
    const int chunk = wid & (K_CHUNKS - 1);
    const int rg    = wid >> 2;              // [0, 1440)
    const int v     = rg >> 3;
    const int det   = ((rg & 7) << 6) | lane;

    float sx = src_pos[2 * v];
    float sy = src_pos[2 * v + 1];
    const float ux = det_u[2 * v];
    const float uy = det_u[2 * v + 1];
    const float u  = ((float)det - 255.5f) * 2.0f;   // DET_SPACING = 2
    float ex = det_center[2 * v]     + u * ux;
    float ey = det_center[2 * v + 1] + u * uy;

    // pick layout so lanes (det direction) run along the fast axis
    const bool useCm = fabsf(uy) >= fabsf(ux);
    if (useCm) {
        float tmp = sx; sx = sy; sy = tmp;
        tmp = ex; ex = ey; ey = tmp;
    }
    const uint2* __restrict__ Qb = (useCm ? Qcm : Qrm) + QOFF;

    const float dx = ex - sx;
    const float dy = ey - sy;
    const float segscl = sqrtf(dx * dx + dy * dy) * (1.0f / (float)N_SAMPLES);
    const float bx = sx + 255.5f;
    const float by = sy + 255.5f;

    // slab clip of t in [0,1] against world box (-256.5, 256.5)^2 (perf only)
    const float lo = -256.5f, hi = 256.5f;
    float t0 = 0.f, t1 = 1.f;
    if (fabsf(dx) > 1e-12f) {
        float ta = (lo - sx) / dx, tb = (hi - sx) / dx;
        t0 = fmaxf(t0, fminf(ta, tb));
        t1 = fminf(t1, fmaxf(ta, tb));
    } else if (sx <= lo || sx >= hi) {
        t1 = -1.f;
    }
    if (fabsf(dy) > 1e-12f) {
        float ta = (lo - sy) / dy, tb = (hi - sy) / dy;
        t0 = fmaxf(t0, fminf(ta, tb));
        t1 = fminf(t1, fmaxf(ta, tb));
    } else if (sy <= lo || sy >= hi) {
        t1 = -1.f;
    }
    // sentinels so a missing lane can't widen the wave bounds
    int s0 = 1 << 20, s1 = -(1 << 20);
    if (t1 >= t0) {
        s0 = max(0, (int)floorf(t0 * (float)N_SAMPLES - 0.5f) - 1);
        s1 = min(N_SAMPLES - 1, (int)ceilf(t1 * (float)N_SAMPLES - 0.5f) + 1);
    }

    // wave-uniform sample range
    int s0w = s0, s1w = s1;
    #pragma unroll
    for (int off = 32; off >= 1; off >>= 1) {
        s0w = min(s0w, __shfl_xor(s0w, off));
        s1w = max(s1w, __shfl_xor(s1w, off));
    }
    int len = s1w - s0w + 1;
    if (len < 0) len = 0;
    const int c0 = s0w + ((len * chunk) >> 2);
    const int c1 = s0w + ((len * (chunk + 1)) >> 2) - 1;

    float t = ((float)c0 + 0.5f) * (1.0f / (float)N_SAMPLES);  // exact
    float acc0 = 0.f, acc1 = 0.f;
    int s = c0;
    for (; s + 1 <= c1; s += 2) {
        acc0 = sample_h(Qb, t,                 dx, dy, bx, by, acc0);
        acc1 = sample_h(Qb, t + 0.001953125f,  dx, dy, bx, by, acc1); // +1/512
        t += 0.00390625f;                                             // +2/512
    }
    if (s <= c1) acc0 = sample_h(Qb, t, dx, dy, bx, by, acc0);

    const float res = (acc0 + acc1) * segscl;
    atomicAdd(&sino[(v << 9) | det], res);
}

// ---------------------------------------------------------------------------
// Fallback path kernels (small workspace): R4's single-layout wave-per-ray,
// and the plain no-workspace projector.
// ---------------------------------------------------------------------------
__global__ __launch_bounds__(256) void add_kernel(const float4* __restrict__ x,
                                                  const float4* __restrict__ r,
                                                  float4* __restrict__ upd) {
    int i = blockIdx.x * blockDim.x + threadIdx.x;
    float4 a = x[i];
    float4 b = r[i];
    upd[i] = make_float4(a.x + b.x, a.y + b.y, a.z + b.z, a.w + b.w);
}
__global__ __launch_bounds__(256) void relu_kernel(const float4* __restrict__ upd,
                                                   float4* __restrict__ out) {
    int i = blockIdx.x * blockDim.x + threadIdx.x;
    float4 c = upd[i];
    out[i] = make_float4(fmaxf(c.x, 0.f), fmaxf(c.y, 0.f),
                         fmaxf(c.z, 0.f), fmaxf(c.w, 0.f));
}

__device__ __forceinline__ void ray_setup(
        const float* __restrict__ src_pos, const float* __restrict__ det_center,
        const float* __restrict__ det_u, int wid,
        float& dx, float& dy, float& bx, float& by, float& seg,
        int& s0, int& s1) {
    const int v   = wid >> 9;
    const int det = wid & 511;
    const float sx = src_pos[2 * v];
    const float sy = src_pos[2 * v + 1];
    const float u  = ((float)det - 255.5f) * 2.0f;
    const float ex = det_center[2 * v]     + u * det_u[2 * v];
    const float ey = det_center[2 * v + 1] + u * det_u[2 * v + 1];
    dx = ex - sx;
    dy = ey - sy;
    seg = sqrtf(dx * dx + dy * dy);
    bx = sx + 255.5f;
    by = sy + 255.5f;
    const float lo = -256.5f, hi = 256.5f;
    float t0 = 0.f, t1 = 1.f;
    if (fabsf(dx) > 1e-12f) {
        float ta = (lo - sx) / dx, tb = (hi - sx) / dx;
        t0 = fmaxf(t0, fminf(ta, tb));
        t1 = fminf(t1, fmaxf(ta, tb));
    } else if (sx <= lo || sx >= hi) {
        t1 = -1.f;
    }
    if (fabsf(dy) > 1e-12f) {
        float ta = (lo - sy) / dy, tb = (hi - sy) / dy;
        t0 = fmaxf(t0, fminf(ta, tb));
        t1 = fminf(t1, fmaxf(ta, tb));
    } else if (sy <= lo || sy >= hi) {
        t1 = -1.f;
    }
    s0 = 0; s1 = -1;
    if (t1 >= t0) {
        s0 = max(0, (int)floorf(t0 * (float)N_SAMPLES - 0.5f) - 1);
        s1 = min(N_SAMPLES - 1, (int)ceilf(t1 * (float)N_SAMPLES - 0.5f) + 1);
    }
}

__global__ __launch_bounds__(256) void pack_half_kernel(
        const float* __restrict__ x, const float* __restrict__ r,
        uint2* __restrict__ Q) {
    int i = blockIdx.x * blockDim.x + threadIdx.x;
    if (i >= Q_N) return;
    int row = i / QDIM;
    int col = i - row * QDIM;
    int iy0 = row - 2, ix0 = col - 2;
    const bool y0v = (unsigned)iy0 < (unsigned)IMG_H;
    const bool y1v = (unsigned)(iy0 + 1) < (unsigned)IMG_H;
    const bool x0v = (unsigned)ix0 < (unsigned)IMG_W;
    const bool x1v = (unsigned)(ix0 + 1) < (unsigned)IMG_W;
    float v00 = 0.f, v01 = 0.f, v10 = 0.f, v11 = 0.f;
    if (y0v) {
        int base = iy0 * IMG_W;
        if (x0v) v00 = x[base + ix0] + r[base + ix0];
        if (x1v) v01 = x[base + ix0 + 1] + r[base + ix0 + 1];
    }
    if (y1v) {
        int base = (iy0 + 1) * IMG_W;
        if (x0v) v10 = x[base + ix0] + r[base + ix0];
        if (x1v) v11 = x[base + ix0 + 1] + r[base + ix0 + 1];
    }
    __half2 lo = __floats2half2_rn(v00, v01);
    __half2 hi = __floats2half2_rn(v10, v11);
    Q[i] = make_uint2(*reinterpret_cast<unsigned*>(&lo),
                      *reinterpret_cast<unsigned*>(&hi));
}

__global__ __launch_bounds__(256) void fanproj_half_kernel(
        const uint2* __restrict__ Q,
        const float* __restrict__ src_pos,
        const float* __restrict__ det_center,
        const float* __restrict__ det_u,
        float* __restrict__ sino) {
    const int wid  = (blockIdx.x * blockDim.x + threadIdx.x) >> 6;
    const int lane = threadIdx.x & 63;
    if (wid >= N_RAYS) return;
    float dx, dy, bx, by, seg;
    int s0, s1;
    ray_setup(src_pos, det_center, det_u, wid, dx, dy, bx, by, seg, s0, s1);
    const uint2* Qb = Q + QOFF;
    int s = s0 + lane;
    float tA = ((float)s + 0.5f) * (1.0f / (float)N_SAMPLES);
    float acc0 = 0.f, acc1 = 0.f;
    for (; s + 64 <= s1; s += 128) {
        acc0 = sample_h(Qb, tA,          dx, dy, bx, by, acc0);
        acc1 = sample_h(Qb, tA + 0.125f, dx, dy, bx, by, acc1);
        tA += 0.25f;
    }
    if (s <= s1) acc0 = sample_h(Qb, tA, dx, dy, bx, by, acc0);
    float acc = acc0 + acc1;
    #pragma unroll
    for (int off = 32; off >= 1; off >>= 1) acc += __shfl_xor(acc, off);
    if (lane == 0) sino[wid] = acc * seg * (1.0f / (float)N_SAMPLES);
}

__device__ __forceinline__ float sample_plain(const float* __restrict__ img,
                                              int s, float dx, float dy,
                                              float bx, float by, float acc) {
    const float t  = fmaf((float)s, 1.f / (float)N_SAMPLES,
                          0.5f / (float)N_SAMPLES);
    const float px = fmaf(t, dx, bx);
    const float py = fmaf(t, dy, by);
    const float ix0f = floorf(px);
    const float iy0f = floorf(py);
    const float fx = px - ix0f;
    const float fy = py - iy0f;
    const int ix0 = (int)ix0f;
    const int iy0 = (int)iy0f;
    const float gx = ((unsigned)ix0       < (unsigned)IMG_W) ? (1.f - fx) : 0.f;
    const float hx = ((unsigned)(ix0 + 1) < (unsigned)IMG_W) ? fx         : 0.f;
    const float gy = ((unsigned)iy0       < (unsigned)IMG_H) ? (1.f - fy) : 0.f;
    const float hy = ((unsigned)(iy0 + 1) < (unsigned)IMG_H) ? fy         : 0.f;
    const unsigned cx0 = (unsigned)min(max(ix0, 0), IMG_W - 1);
    const unsigned cx1 = (unsigned)min(max(ix0 + 1, 0), IMG_W - 1);
    const unsigned r0  = (unsigned)min(max(iy0, 0), IMG_H - 1) << 9;
    const unsigned r1  = (unsigned)min(max(iy0 + 1, 0), IMG_H - 1) << 9;
    const float v00 = img[r0 + cx0];
    const float v01 = img[r0 + cx1];
    const float v10 = img[r1 + cx0];
    const float v11 = img[r1 + cx1];
    acc = fmaf(v00, gx * gy, acc);
    acc = fmaf(v01, hx * gy, acc);
    acc = fmaf(v10, gx * hy, acc);
    acc = fmaf(v11, hx * hy, acc);
    return acc;
}

__global__ __launch_bounds__(256) void fanproj_plain_kernel(
        const float* __restrict__ img,
        const float* __restrict__ src_pos,
        const float* __restrict__ det_center,
        const float* __restrict__ det_u,
        float* __restrict__ sino) {
    const int wid  = (blockIdx.x * blockDim.x + threadIdx.x) >> 6;
    const int lane = threadIdx.x & 63;
    if (wid >= N_RAYS) return;
    float dx, dy, bx, by, seg;
    int s0, s1;
    ray_setup(src_pos, det_center, det_u, wid, dx, dy, bx, by, seg, s0, s1);
    float acc0 = 0.f, acc1 = 0.f;
    int s = s0 + lane;
    for (; s + 64 <= s1; s += 128) {
        acc0 = sample_plain(img, s,      dx, dy, bx, by, acc0);
        acc1 = sample_plain(img, s + 64, dx, dy, bx, by, acc1);
    }
    if (s <= s1) acc0 = sample_plain(img, s, dx, dy, bx, by, acc0);
    float acc = acc0 + acc1;
    #pragma unroll
    for (int off = 32; off >= 1; off >>= 1) acc += __shfl_xor(acc, off);
    if (lane == 0) sino[wid] = acc * seg * (1.0f / (float)N_SAMPLES);
}

// ---------------------------------------------------------------------------
extern "C" void kernel_launch(void* const* d_in, const int* in_sizes, int n_in,
                              void* d_out, int out_size, void* d_ws, size_t ws_size,
                              hipStream_t stream) {
    const float* x          = (const float*)d_in[0];
    const float* reco       = (const float*)d_in[1];
    const float* src_pos    = (const float*)d_in[2];
    const float* det_center = (const float*)d_in[3];
    const float* det_u      = (const float*)d_in[4];

    float* out  = (float*)d_out;
    float* sino = out;                 // [180*512]
    float* relu = out + N_RAYS;        // [512*512]

    const int n4 = IMG_N / 4;          // 65536

    if (ws_size >= 2 * Q_BYTES) {
        // primary: dual-layout arc projector with chunked atomics
        uint2* Qrm = (uint2*)d_ws;
        uint2* Qcm = (uint2*)((char*)d_ws + Q_BYTES);
        hipMemsetAsync(sino, 0, N_RAYS * sizeof(float), stream);
        add_relu_kernel<<<n4 / 256, 256, 0, stream>>>(
            (const float4*)x, (const float4*)reco, (float4*)relu);
        pack_dual_kernel<<<(Q_N + 255) / 256, 256, 0, stream>>>(x, reco, Qrm, Qcm);
        fanproj_arc_kernel<<<(N_WAVES * 64) / 256, 256, 0, stream>>>(
            Qrm, Qcm, src_pos, det_center, det_u, sino);
    } else if (ws_size >= Q_BYTES) {
        // fallback: single-layout wave-per-ray (R4 path)
        uint2* Q = (uint2*)d_ws;
        add_relu_kernel<<<n4 / 256, 256, 0, stream>>>(
            (const float4*)x, (const float4*)reco, (float4*)relu);
        pack_half_kernel<<<(Q_N + 255) / 256, 256, 0, stream>>>(x, reco, Q);
        fanproj_half_kernel<<<N_RAYS / 4, 256, 0, stream>>>(
            Q, src_pos, det_center, det_u, sino);
    } else {
        // minimal fallback: upd lives in the relu output region
        float* upd = relu;
        add_kernel<<<n4 / 256, 256, 0, stream>>>(
            (const float4*)x, (const float4*)reco, (float4*)upd);
        fanproj_plain_kernel<<<N_RAYS / 4, 256, 0, stream>>>(
            upd, src_pos, det_center, det_u, sino);
        relu_kernel<<<n4 / 256, 256, 0, stream>>>(
            (const float4*)upd, (float4*)relu);
    }
}

// Round 6
// 53.705 us; speedup vs baseline: 1.1664x; 1.1664x over previous
//
#include <hip/hip_runtime.h>
#include <hip/hip_bf16.h>
#include <hip/hip_fp16.h>

// Problem constants (from reference)
#define IMG_H 512
#define IMG_W 512
#define N_VIEWS 180
#define N_DET 512
#define N_SAMPLES 512

#define N_RAYS (N_VIEWS * N_DET)          // 92160
#define IMG_N (IMG_H * IMG_W)             // 262144
#define IMG_BYTES (IMG_N * sizeof(float)) // 1 MiB

// fp16 packed-quad grids with a 2-ring zero pad, TWO layouts:
//  Qrm[(iy0+2)*QDIM + (ix0+2)] = half4{ v00=I[iy0][ix0],   v01=I[iy0][ix0+1],
//                                       v10=I[iy0+1][ix0], v11=I[iy0+1][ix0+1] }
//  Qcm[(ix0+2)*QDIM + (iy0+2)] = half4{ v00, v10, v01, v11 }   (transposed)
// for ix0,iy0 in [-2,512], I==0 outside [0,512)^2. Clamping the float coord
// to [-2,512] always lands on a quad reproducing the reference's zero-outside
// gather exactly (all-zero quad when the clamp engages).
#define QDIM 515
#define Q_N (QDIM * QDIM)                 // 265225
#define Q_BYTES ((size_t)Q_N * sizeof(uint2))  // ~2.1 MiB
#define QOFF (2 * QDIM + 2)

#define K_CHUNKS 16
#define RAYINFO_BYTES ((size_t)N_RAYS * 32)

// ---------------------------------------------------------------------------
// k1: pack Qrm (row-major quads) from x+reco, coalesced writes; ALSO emits
//     relu(x+reco) for the interior threads (each pixel covered exactly once).
// ---------------------------------------------------------------------------
__global__ __launch_bounds__(256) void pack_rm_relu_kernel(
        const float* __restrict__ x, const float* __restrict__ r,
        uint2* __restrict__ Qrm, float* __restrict__ relu_out) {
    int i = blockIdx.x * blockDim.x + threadIdx.x;
    if (i >= Q_N) return;
    int row = i / QDIM;
    int col = i - row * QDIM;
    int iy0 = row - 2, ix0 = col - 2;
    const bool y0v = (unsigned)iy0 < (unsigned)IMG_H;
    const bool y1v = (unsigned)(iy0 + 1) < (unsigned)IMG_H;
    const bool x0v = (unsigned)ix0 < (unsigned)IMG_W;
    const bool x1v = (unsigned)(ix0 + 1) < (unsigned)IMG_W;
    float v00 = 0.f, v01 = 0.f, v10 = 0.f, v11 = 0.f;
    if (y0v) {
        int base = iy0 * IMG_W;
        if (x0v) v00 = x[base + ix0] + r[base + ix0];
        if (x1v) v01 = x[base + ix0 + 1] + r[base + ix0 + 1];
    }
    if (y1v) {
        int base = (iy0 + 1) * IMG_W;
        if (x0v) v10 = x[base + ix0] + r[base + ix0];
        if (x1v) v11 = x[base + ix0 + 1] + r[base + ix0 + 1];
    }
    __half2 lo = __floats2half2_rn(v00, v01);
    __half2 hi = __floats2half2_rn(v10, v11);
    Qrm[i] = make_uint2(*reinterpret_cast<unsigned*>(&lo),
                        *reinterpret_cast<unsigned*>(&hi));
    // relu output: thread (row,col) owns pixel (iy0,ix0) when in range
    if (y0v && x0v) relu_out[iy0 * IMG_W + ix0] = fmaxf(v00, 0.f);
}

// ---------------------------------------------------------------------------
// k2: build Qcm from Qrm. Linear (coalesced) writes; strided reads hit L2.
//     Qcm[col*QDIM+row] = swizzle(Qrm[row*QDIM+col]):
//       {h(v00)|h(v01), h(v10)|h(v11)} -> {h(v00)|h(v10), h(v01)|h(v11)}
// ---------------------------------------------------------------------------
__global__ __launch_bounds__(256) void pack_cm_kernel(
        const uint2* __restrict__ Qrm, uint2* __restrict__ Qcm) {
    int j = blockIdx.x * blockDim.x + threadIdx.x;
    if (j >= Q_N) return;
    int col = j / QDIM;
    int row = j - col * QDIM;
    uint2 q = Qrm[row * QDIM + col];
    unsigned lo = (q.x & 0x0000FFFFu) | (q.y << 16);
    unsigned hi = (q.x >> 16) | (q.y & 0xFFFF0000u);
    Qcm[j] = make_uint2(lo, hi);
}

// ---------------------------------------------------------------------------
// k3: per-ray setup -> RA[rid]={dx,dy,bx,by}, RB[rid]={segscl,s0,len,useCm}
//     (coords already swapped for transposed-layout views)
// ---------------------------------------------------------------------------
__global__ __launch_bounds__(256) void ray_setup_kernel(
        const float* __restrict__ src_pos,
        const float* __restrict__ det_center,
        const float* __restrict__ det_u,
        float4* __restrict__ RA, float4* __restrict__ RB) {
    const int rid = blockIdx.x * blockDim.x + threadIdx.x;  // 360 blocks exact
    const int v   = rid >> 9;
    const int det = rid & 511;

    float sx = src_pos[2 * v];
    float sy = src_pos[2 * v + 1];
    const float ux = det_u[2 * v];
    const float uy = det_u[2 * v + 1];
    const float u  = ((float)det - 255.5f) * 2.0f;   // DET_SPACING = 2
    float ex = det_center[2 * v]     + u * ux;
    float ey = det_center[2 * v + 1] + u * uy;

    const bool useCm = fabsf(uy) >= fabsf(ux);
    if (useCm) {
        float tmp = sx; sx = sy; sy = tmp;
        tmp = ex; ex = ey; ey = tmp;
    }
    const float dx = ex - sx;
    const float dy = ey - sy;
    const float segscl = sqrtf(dx * dx + dy * dy) * (1.0f / (float)N_SAMPLES);

    // slab clip of t in [0,1] against world box (-256.5, 256.5)^2 (perf only)
    const float lo = -256.5f, hi = 256.5f;
    float t0 = 0.f, t1 = 1.f;
    if (fabsf(dx) > 1e-12f) {
        float ta = (lo - sx) / dx, tb = (hi - sx) / dx;
        t0 = fmaxf(t0, fminf(ta, tb));
        t1 = fminf(t1, fmaxf(ta, tb));
    } else if (sx <= lo || sx >= hi) {
        t1 = -1.f;
    }
    if (fabsf(dy) > 1e-12f) {
        float ta = (lo - sy) / dy, tb = (hi - sy) / dy;
        t0 = fmaxf(t0, fminf(ta, tb));
        t1 = fminf(t1, fmaxf(ta, tb));
    } else if (sy <= lo || sy >= hi) {
        t1 = -1.f;
    }
    int s0 = 0, len = 0;
    if (t1 >= t0) {
        s0 = max(0, (int)floorf(t0 * (float)N_SAMPLES - 0.5f) - 1);
        int s1 = min(N_SAMPLES - 1, (int)ceilf(t1 * (float)N_SAMPLES - 0.5f) + 1);
        len = s1 - s0 + 1;
        if (len < 0) len = 0;
    }
    RA[rid] = make_float4(dx, dy, sx + 255.5f, sy + 255.5f);
    RB[rid] = make_float4(segscl, (float)s0, (float)len, useCm ? 1.f : 0.f);
}

// ---------------------------------------------------------------------------
// fp16 packed-quad bilinear sample: ONE 8B gather, no masking.
// ---------------------------------------------------------------------------
__device__ __forceinline__ float sample_h(const uint2* __restrict__ Qb,
                                          float t, float dx, float dy,
                                          float bx, float by, float acc) {
    float px = fmaf(t, dx, bx);
    float py = fmaf(t, dy, by);
    px = __builtin_amdgcn_fmed3f(px, -2.0f, 512.0f);
    py = __builtin_amdgcn_fmed3f(py, -2.0f, 512.0f);
    const float ixf = floorf(px);
    const float iyf = floorf(py);
    const float fx = px - ixf;
    const float fy = py - iyf;
    const int lin = (int)iyf * QDIM + (int)ixf;

    const uint2 qw = Qb[lin];
    const float2 fa = __half22float2(*reinterpret_cast<const __half2*>(&qw.x));
    const float2 fb = __half22float2(*reinterpret_cast<const __half2*>(&qw.y));

    const float gx = 1.f - fx;
    const float gy = 1.f - fy;
    const float h0 = fmaf(fx, fa.y, gx * fa.x);
    const float h1 = fmaf(fx, fb.y, gx * fb.x);
    acc = fmaf(gy, h0, acc);
    acc = fmaf(fy, h1, acc);
    return acc;
}

// ---------------------------------------------------------------------------
// k4: fan-beam projection. THREAD = (ray, 1/16 sample-chunk).
//   rid = blockIdx.x*256+threadIdx.x -> lanes are 64 consecutive dets of one
//   view: at equal t they form a compact segment along the chosen layout's
//   fast axis. All per-ray setup preloaded from RA/RB.
// ---------------------------------------------------------------------------
__global__ __launch_bounds__(256) void fanproj_arc_kernel(
        const uint2* __restrict__ Qrm, const uint2* __restrict__ Qcm,
        const float4* __restrict__ RA, const float4* __restrict__ RB,
        float* __restrict__ sino) {
    const int rid   = blockIdx.x * blockDim.x + threadIdx.x;
    const int chunk = blockIdx.y;

    const float4 a = RA[rid];
    const float4 b = RB[rid];
    const float dx = a.x, dy = a.y, bx = a.z, by = a.w;
    const float segscl = b.x;
    const int s0  = (int)b.y;
    const int len = (int)b.z;
    const uint2* __restrict__ Qb = (b.w != 0.f ? Qcm : Qrm) + QOFF;

    const int c0 = s0 + ((len * chunk) >> 4);
    const int c1 = s0 + ((len * (chunk + 1)) >> 4) - 1;

    float t = ((float)c0 + 0.5f) * (1.0f / (float)N_SAMPLES);  // exact
    float acc0 = 0.f, acc1 = 0.f, acc2 = 0.f, acc3 = 0.f;
    int s = c0;
    for (; s + 3 <= c1; s += 4) {
        acc0 = sample_h(Qb, t,                dx, dy, bx, by, acc0);
        acc1 = sample_h(Qb, t + 0.001953125f, dx, dy, bx, by, acc1); // +1/512
        acc2 = sample_h(Qb, t + 0.00390625f,  dx, dy, bx, by, acc2); // +2/512
        acc3 = sample_h(Qb, t + 0.005859375f, dx, dy, bx, by, acc3); // +3/512
        t += 0.0078125f;                                             // +4/512
    }
    for (; s <= c1; ++s) {
        acc0 = sample_h(Qb, t, dx, dy, bx, by, acc0);
        t += 0.001953125f;
    }

    const float res = ((acc0 + acc1) + (acc2 + acc3)) * segscl;
    if (res != 0.f) atomicAdd(&sino[rid], res);
}

// ---------------------------------------------------------------------------
// Fallback path kernels (small workspace)
// ---------------------------------------------------------------------------
__global__ __launch_bounds__(256) void add_relu_kernel(
        const float4* __restrict__ x, const float4* __restrict__ r,
        float4* __restrict__ out_relu) {
    int i = blockIdx.x * blockDim.x + threadIdx.x;
    float4 a = x[i];
    float4 b = r[i];
    out_relu[i] = make_float4(fmaxf(a.x + b.x, 0.f), fmaxf(a.y + b.y, 0.f),
                              fmaxf(a.z + b.z, 0.f), fmaxf(a.w + b.w, 0.f));
}
__global__ __launch_bounds__(256) void add_kernel(const float4* __restrict__ x,
                                                  const float4* __restrict__ r,
                                                  float4* __restrict__ upd) {
    int i = blockIdx.x * blockDim.x + threadIdx.x;
    float4 a = x[i];
    float4 b = r[i];
    upd[i] = make_float4(a.x + b.x, a.y + b.y, a.z + b.z, a.w + b.w);
}
__global__ __launch_bounds__(256) void relu_kernel(const float4* __restrict__ upd,
                                                   float4* __restrict__ out) {
    int i = blockIdx.x * blockDim.x + threadIdx.x;
    float4 c = upd[i];
    out[i] = make_float4(fmaxf(c.x, 0.f), fmaxf(c.y, 0.f),
                         fmaxf(c.z, 0.f), fmaxf(c.w, 0.f));
}

__device__ __forceinline__ void ray_setup(
        const float* __restrict__ src_pos, const float* __restrict__ det_center,
        const float* __restrict__ det_u, int wid,
        float& dx, float& dy, float& bx, float& by, float& seg,
        int& s0, int& s1) {
    const int v   = wid >> 9;
    const int det = wid & 511;
    const float sx = src_pos[2 * v];
    const float sy = src_pos[2 * v + 1];
    const float u  = ((float)det - 255.5f) * 2.0f;
    const float ex = det_center[2 * v]     + u * det_u[2 * v];
    const float ey = det_center[2 * v + 1] + u * det_u[2 * v + 1];
    dx = ex - sx;
    dy = ey - sy;
    seg = sqrtf(dx * dx + dy * dy);
    bx = sx + 255.5f;
    by = sy + 255.5f;
    const float lo = -256.5f, hi = 256.5f;
    float t0 = 0.f, t1 = 1.f;
    if (fabsf(dx) > 1e-12f) {
        float ta = (lo - sx) / dx, tb = (hi - sx) / dx;
        t0 = fmaxf(t0, fminf(ta, tb));
        t1 = fminf(t1, fmaxf(ta, tb));
    } else if (sx <= lo || sx >= hi) {
        t1 = -1.f;
    }
    if (fabsf(dy) > 1e-12f) {
        float ta = (lo - sy) / dy, tb = (hi - sy) / dy;
        t0 = fmaxf(t0, fminf(ta, tb));
        t1 = fminf(t1, fmaxf(ta, tb));
    } else if (sy <= lo || sy >= hi) {
        t1 = -1.f;
    }
    s0 = 0; s1 = -1;
    if (t1 >= t0) {
        s0 = max(0, (int)floorf(t0 * (float)N_SAMPLES - 0.5f) - 1);
        s1 = min(N_SAMPLES - 1, (int)ceilf(t1 * (float)N_SAMPLES - 0.5f) + 1);
    }
}

__global__ __launch_bounds__(256) void pack_half_kernel(
        const float* __restrict__ x, const float* __restrict__ r,
        uint2* __restrict__ Q) {
    int i = blockIdx.x * blockDim.x + threadIdx.x;
    if (i >= Q_N) return;
    int row = i / QDIM;
    int col = i - row * QDIM;
    int iy0 = row - 2, ix0 = col - 2;
    const bool y0v = (unsigned)iy0 < (unsigned)IMG_H;
    const bool y1v = (unsigned)(iy0 + 1) < (unsigned)IMG_H;
    const bool x0v = (unsigned)ix0 < (unsigned)IMG_W;
    const bool x1v = (unsigned)(ix0 + 1) < (unsigned)IMG_W;
    float v00 = 0.f, v01 = 0.f, v10 = 0.f, v11 = 0.f;
    if (y0v) {
        int base = iy0 * IMG_W;
        if (x0v) v00 = x[base + ix0] + r[base + ix0];
        if (x1v) v01 = x[base + ix0 + 1] + r[base + ix0 + 1];
    }
    if (y1v) {
        int base = (iy0 + 1) * IMG_W;
        if (x0v) v10 = x[base + ix0] + r[base + ix0];
        if (x1v) v11 = x[base + ix0 + 1] + r[base + ix0 + 1];
    }
    __half2 lo = __floats2half2_rn(v00, v01);
    __half2 hi = __floats2half2_rn(v10, v11);
    Q[i] = make_uint2(*reinterpret_cast<unsigned*>(&lo),
                      *reinterpret_cast<unsigned*>(&hi));
}

__global__ __launch_bounds__(256) void fanproj_half_kernel(
        const uint2* __restrict__ Q,
        const float* __restrict__ src_pos,
        const float* __restrict__ det_center,
        const float* __restrict__ det_u,
        float* __restrict__ sino) {
    const int wid  = (blockIdx.x * blockDim.x + threadIdx.x) >> 6;
    const int lane = threadIdx.x & 63;
    if (wid >= N_RAYS) return;
    float dx, dy, bx, by, seg;
    int s0, s1;
    ray_setup(src_pos, det_center, det_u, wid, dx, dy, bx, by, seg, s0, s1);
    const uint2* Qb = Q + QOFF;
    int s = s0 + lane;
    float tA = ((float)s + 0.5f) * (1.0f / (float)N_SAMPLES);
    float acc0 = 0.f, acc1 = 0.f;
    for (; s + 64 <= s1; s += 128) {
        acc0 = sample_h(Qb, tA,          dx, dy, bx, by, acc0);
        acc1 = sample_h(Qb, tA + 0.125f, dx, dy, bx, by, acc1);
        tA += 0.25f;
    }
    if (s <= s1) acc0 = sample_h(Qb, tA, dx, dy, bx, by, acc0);
    float acc = acc0 + acc1;
    #pragma unroll
    for (int off = 32; off >= 1; off >>= 1) acc += __shfl_xor(acc, off);
    if (lane == 0) sino[wid] = acc * seg * (1.0f / (float)N_SAMPLES);
}

__device__ __forceinline__ float sample_plain(const float* __restrict__ img,
                                              int s, float dx, float dy,
                                              float bx, float by, float acc) {
    const float t  = fmaf((float)s, 1.f / (float)N_SAMPLES,
                          0.5f / (float)N_SAMPLES);
    const float px = fmaf(t, dx, bx);
    const float py = fmaf(t, dy, by);
    const float ix0f = floorf(px);
    const float iy0f = floorf(py);
    const float fx = px - ix0f;
    const float fy = py - iy0f;
    const int ix0 = (int)ix0f;
    const int iy0 = (int)iy0f;
    const float gx = ((unsigned)ix0       < (unsigned)IMG_W) ? (1.f - fx) : 0.f;
    const float hx = ((unsigned)(ix0 + 1) < (unsigned)IMG_W) ? fx         : 0.f;
    const float gy = ((unsigned)iy0       < (unsigned)IMG_H) ? (1.f - fy) : 0.f;
    const float hy = ((unsigned)(iy0 + 1) < (unsigned)IMG_H) ? fy         : 0.f;
    const unsigned cx0 = (unsigned)min(max(ix0, 0), IMG_W - 1);
    const unsigned cx1 = (unsigned)min(max(ix0 + 1, 0), IMG_W - 1);
    const unsigned r0  = (unsigned)min(max(iy0, 0), IMG_H - 1) << 9;
    const unsigned r1  = (unsigned)min(max(iy0 + 1, 0), IMG_H - 1) << 9;
    const float v00 = img[r0 + cx0];
    const float v01 = img[r0 + cx1];
    const float v10 = img[r1 + cx0];
    const float v11 = img[r1 + cx1];
    acc = fmaf(v00, gx * gy, acc);
    acc = fmaf(v01, hx * gy, acc);
    acc = fmaf(v10, gx * hy, acc);
    acc = fmaf(v11, hx * hy, acc);
    return acc;
}

__global__ __launch_bounds__(256) void fanproj_plain_kernel(
        const float* __restrict__ img,
        const float* __restrict__ src_pos,
        const float* __restrict__ det_center,
        const float* __restrict__ det_u,
        float* __restrict__ sino) {
    const int wid  = (blockIdx.x * blockDim.x + threadIdx.x) >> 6;
    const int lane = threadIdx.x & 63;
    if (wid >= N_RAYS) return;
    float dx, dy, bx, by, seg;
    int s0, s1;
    ray_setup(src_pos, det_center, det_u, wid, dx, dy, bx, by, seg, s0, s1);
    float acc0 = 0.f, acc1 = 0.f;
    int s = s0 + lane;
    for (; s + 64 <= s1; s += 128) {
        acc0 = sample_plain(img, s,      dx, dy, bx, by, acc0);
        acc1 = sample_plain(img, s + 64, dx, dy, bx, by, acc1);
    }
    if (s <= s1) acc0 = sample_plain(img, s, dx, dy, bx, by, acc0);
    float acc = acc0 + acc1;
    #pragma unroll
    for (int off = 32; off >= 1; off >>= 1) acc += __shfl_xor(acc, off);
    if (lane == 0) sino[wid] = acc * seg * (1.0f / (float)N_SAMPLES);
}

// ---------------------------------------------------------------------------
extern "C" void kernel_launch(void* const* d_in, const int* in_sizes, int n_in,
                              void* d_out, int out_size, void* d_ws, size_t ws_size,
                              hipStream_t stream) {
    const float* x          = (const float*)d_in[0];
    const float* reco       = (const float*)d_in[1];
    const float* src_pos    = (const float*)d_in[2];
    const float* det_center = (const float*)d_in[3];
    const float* det_u      = (const float*)d_in[4];

    float* out  = (float*)d_out;
    float* sino = out;                 // [180*512]
    float* relu = out + N_RAYS;        // [512*512]

    const int n4 = IMG_N / 4;          // 65536
    const int qblocks = (Q_N + 255) / 256;

    if (ws_size >= 2 * Q_BYTES + RAYINFO_BYTES) {
        // primary: dual-layout arc projector, precomputed ray setup, 16 chunks
        uint2*  Qrm = (uint2*)d_ws;
        uint2*  Qcm = (uint2*)((char*)d_ws + Q_BYTES);
        float4* RA  = (float4*)((char*)d_ws + 2 * Q_BYTES);
        float4* RB  = RA + N_RAYS;
        hipMemsetAsync(sino, 0, N_RAYS * sizeof(float), stream);
        pack_rm_relu_kernel<<<qblocks, 256, 0, stream>>>(x, reco, Qrm, relu);
        pack_cm_kernel<<<qblocks, 256, 0, stream>>>(Qrm, Qcm);
        ray_setup_kernel<<<N_RAYS / 256, 256, 0, stream>>>(
            src_pos, det_center, det_u, RA, RB);
        fanproj_arc_kernel<<<dim3(N_RAYS / 256, K_CHUNKS), 256, 0, stream>>>(
            Qrm, Qcm, RA, RB, sino);
    } else if (ws_size >= Q_BYTES) {
        // fallback: single-layout wave-per-ray (R4 path)
        uint2* Q = (uint2*)d_ws;
        add_relu_kernel<<<n4 / 256, 256, 0, stream>>>(
            (const float4*)x, (const float4*)reco, (float4*)relu);
        pack_half_kernel<<<qblocks, 256, 0, stream>>>(x, reco, Q);
        fanproj_half_kernel<<<N_RAYS / 4, 256, 0, stream>>>(
            Q, src_pos, det_center, det_u, sino);
    } else {
        // minimal fallback: upd lives in the relu output region
        float* upd = relu;
        add_kernel<<<n4 / 256, 256, 0, stream>>>(
            (const float4*)x, (const float4*)reco, (float4*)upd);
        fanproj_plain_kernel<<<N_RAYS / 4, 256, 0, stream>>>(
            upd, src_pos, det_center, det_u, sino);
        relu_kernel<<<n4 / 256, 256, 0, stream>>>(
            (const float4*)upd, (float4*)relu);
    }
}

// Round 7
// 44.260 us; speedup vs baseline: 1.4153x; 1.2134x over previous
//
#include <hip/hip_runtime.h>
#include <hip/hip_bf16.h>
#include <hip/hip_fp16.h>

// Problem constants (from reference)
#define IMG_H 512
#define IMG_W 512
#define N_VIEWS 180
#define N_DET 512
#define N_SAMPLES 512

#define N_RAYS (N_VIEWS * N_DET)          // 92160
#define IMG_N (IMG_H * IMG_W)             // 262144

// fp16 packed-quad grid, single row-major layout, 8-px zero pad ring:
//   Q[(iy0+8)*QDIM + (ix0+8)] = half4{ I[iy0][ix0],   I[iy0][ix0+1],
//                                      I[iy0+1][ix0], I[iy0+1][ix0+1] }
// for ix0,iy0 in [-8, 520], I==0 outside [0,512)^2.
// The slab clip widens the sample range by <= ~6.4 px beyond the box, so all
// touched quads lie inside the pad -> NO per-sample clamping needed, and all
// out-of-image taps are exact zeros (reference semantics).
#define QPAD 8
#define QDIM (IMG_W + 1 + 2 * QPAD)       // 529
#define Q_N (QDIM * QDIM)                 // 279841
#define Q_BYTES ((size_t)Q_N * sizeof(uint2))   // ~2.24 MiB
#define RAYINFO_BYTES ((size_t)N_RAYS * 32)

#define K_CHUNKS 4

// ---------------------------------------------------------------------------
// k1: pack Q (row-major fp16 quads) from x+reco; also emits relu(x+reco)
//     (each image pixel is owned by exactly one thread).
// ---------------------------------------------------------------------------
__global__ __launch_bounds__(256) void pack_q_relu_kernel(
        const float* __restrict__ x, const float* __restrict__ r,
        uint2* __restrict__ Q, float* __restrict__ relu_out) {
    int i = blockIdx.x * blockDim.x + threadIdx.x;
    if (i >= Q_N) return;
    int row = i / QDIM;
    int col = i - row * QDIM;
    int iy0 = row - QPAD, ix0 = col - QPAD;
    const bool y0v = (unsigned)iy0 < (unsigned)IMG_H;
    const bool y1v = (unsigned)(iy0 + 1) < (unsigned)IMG_H;
    const bool x0v = (unsigned)ix0 < (unsigned)IMG_W;
    const bool x1v = (unsigned)(ix0 + 1) < (unsigned)IMG_W;
    float v00 = 0.f, v01 = 0.f, v10 = 0.f, v11 = 0.f;
    if (y0v) {
        int base = iy0 * IMG_W;
        if (x0v) v00 = x[base + ix0] + r[base + ix0];
        if (x1v) v01 = x[base + ix0 + 1] + r[base + ix0 + 1];
    }
    if (y1v) {
        int base = (iy0 + 1) * IMG_W;
        if (x0v) v10 = x[base + ix0] + r[base + ix0];
        if (x1v) v11 = x[base + ix0 + 1] + r[base + ix0 + 1];
    }
    __half2 lo = __floats2half2_rn(v00, v01);
    __half2 hi = __floats2half2_rn(v10, v11);
    Q[i] = make_uint2(*reinterpret_cast<unsigned*>(&lo),
                      *reinterpret_cast<unsigned*>(&hi));
    if (y0v && x0v) relu_out[iy0 * IMG_W + ix0] = fmaxf(v00, 0.f);
}

// ---------------------------------------------------------------------------
// k2: per-ray setup -> RA[rid]={dx,dy,bx,by}, RB[rid]={segscl,s0,len,0}
//     Also zeroes sino[rid] (replaces hipMemsetAsync).
//     bx/by fold in the +QPAD offset so sample coords are always positive
//     and in-range: floor == trunc, no clamps.
// ---------------------------------------------------------------------------
__global__ __launch_bounds__(256) void ray_setup_kernel(
        const float* __restrict__ src_pos,
        const float* __restrict__ det_center,
        const float* __restrict__ det_u,
        float4* __restrict__ RA, float4* __restrict__ RB,
        float* __restrict__ sino) {
    const int rid = blockIdx.x * blockDim.x + threadIdx.x;  // 360 blocks exact
    const int v   = rid >> 9;
    const int det = rid & 511;

    const float sx = src_pos[2 * v];
    const float sy = src_pos[2 * v + 1];
    const float u  = ((float)det - 255.5f) * 2.0f;   // DET_SPACING = 2
    const float ex = det_center[2 * v]     + u * det_u[2 * v];
    const float ey = det_center[2 * v + 1] + u * det_u[2 * v + 1];

    const float dx = ex - sx;
    const float dy = ey - sy;
    const float segscl = sqrtf(dx * dx + dy * dy) * (1.0f / (float)N_SAMPLES);

    // slab clip of t in [0,1] against world box (-256.5, 256.5)^2 (perf only;
    // overshoot of the +-1-sample widening is <= 6.4 px < QPAD)
    const float lo = -256.5f, hi = 256.5f;
    float t0 = 0.f, t1 = 1.f;
    if (fabsf(dx) > 1e-12f) {
        float ta = (lo - sx) / dx, tb = (hi - sx) / dx;
        t0 = fmaxf(t0, fminf(ta, tb));
        t1 = fminf(t1, fmaxf(ta, tb));
    } else if (sx <= lo || sx >= hi) {
        t1 = -1.f;
    }
    if (fabsf(dy) > 1e-12f) {
        float ta = (lo - sy) / dy, tb = (hi - sy) / dy;
        t0 = fmaxf(t0, fminf(ta, tb));
        t1 = fminf(t1, fmaxf(ta, tb));
    } else if (sy <= lo || sy >= hi) {
        t1 = -1.f;
    }
    int s0 = 0, len = 0;
    if (t1 >= t0) {
        s0 = max(0, (int)floorf(t0 * (float)N_SAMPLES - 0.5f) - 1);
        int s1 = min(N_SAMPLES - 1, (int)ceilf(t1 * (float)N_SAMPLES - 0.5f) + 1);
        len = s1 - s0 + 1;
        if (len < 0) len = 0;
    }
    RA[rid] = make_float4(dx, dy, sx + 255.5f + (float)QPAD,
                                  sy + 255.5f + (float)QPAD);
    RB[rid] = make_float4(segscl, (float)s0, (float)len, 0.f);
    sino[rid] = 0.f;
}

// ---------------------------------------------------------------------------
// fp16 packed-quad bilinear sample: ONE 8B gather, no clamp, no masking.
// px,py guaranteed in (0.6, 526.4) -> trunc == floor, indices in-bounds.
// ---------------------------------------------------------------------------
__device__ __forceinline__ float sample_h(const uint2* __restrict__ Q,
                                          float t, float dx, float dy,
                                          float bx, float by, float acc) {
    const float px = fmaf(t, dx, bx);
    const float py = fmaf(t, dy, by);
    const float ixf = truncf(px);
    const float iyf = truncf(py);
    const float fx = px - ixf;
    const float fy = py - iyf;
    const int lin = (int)iyf * QDIM + (int)ixf;

    const uint2 qw = Q[lin];
    const float2 fa = __half22float2(*reinterpret_cast<const __half2*>(&qw.x));
    const float2 fb = __half22float2(*reinterpret_cast<const __half2*>(&qw.y));

    const float gx = 1.f - fx;
    const float h0 = fmaf(fx, fa.y, gx * fa.x);
    const float h1 = fmaf(fx, fb.y, gx * fb.x);
    acc = fmaf(1.f - fy, h0, acc);
    acc = fmaf(fy, h1, acc);
    return acc;
}

// ---------------------------------------------------------------------------
// k3: fan-beam projection, 2D lane tiling.
//   wave = 16 consecutive dets x 4 sample-offsets -> gather footprint is a
//   compact ~16x10 px blob for EVERY view orientation (no dual layout).
//   block = 256 threads = 64 dets; grid = (1440, K_CHUNKS).
//   Per-ray partial reduced via shfl_xor(16/32); lane soff==0 does one atomic.
// ---------------------------------------------------------------------------
__global__ __launch_bounds__(256) void fanproj_tile_kernel(
        const uint2* __restrict__ Q,
        const float4* __restrict__ RA, const float4* __restrict__ RB,
        float* __restrict__ sino) {
    const int tix  = threadIdx.x;
    const int lane = tix & 63;
    const int dsub = lane & 15;
    const int soff = lane >> 4;                       // 0..3
    const int rid  = blockIdx.x * 64 + ((tix >> 6) << 4) + dsub;
    const int chunk = blockIdx.y;

    const float4 a = RA[rid];
    const float4 b = RB[rid];
    const float dx = a.x, dy = a.y, bx = a.z, by = a.w;
    const int s0  = (int)b.y;
    const int len = (int)b.z;
    const int c0 = s0 + ((len * chunk) >> 2);
    const int c1 = s0 + ((len * (chunk + 1)) >> 2) - 1;

    int s = c0 + soff;
    float t = ((float)s + 0.5f) * (1.0f / (float)N_SAMPLES);  // exact
    float acc0 = 0.f, acc1 = 0.f;
    for (; s + 4 <= c1; s += 8) {
        acc0 = sample_h(Q, t,               dx, dy, bx, by, acc0);
        acc1 = sample_h(Q, t + 0.0078125f,  dx, dy, bx, by, acc1); // +4/512
        t += 0.015625f;                                            // +8/512
    }
    if (s <= c1) acc0 = sample_h(Q, t, dx, dy, bx, by, acc0);

    float acc = acc0 + acc1;
    acc += __shfl_xor(acc, 16);   // sum over the 4 sample-offset groups
    acc += __shfl_xor(acc, 32);
    if (soff == 0) {
        const float res = acc * b.x;
        if (res != 0.f) atomicAdd(&sino[rid], res);
    }
}

// ---------------------------------------------------------------------------
// Minimal fallback path (tiny workspace): plain projector straight from upd.
// ---------------------------------------------------------------------------
__global__ __launch_bounds__(256) void add_kernel(const float4* __restrict__ x,
                                                  const float4* __restrict__ r,
                                                  float4* __restrict__ upd) {
    int i = blockIdx.x * blockDim.x + threadIdx.x;
    float4 a = x[i];
    float4 b = r[i];
    upd[i] = make_float4(a.x + b.x, a.y + b.y, a.z + b.z, a.w + b.w);
}
__global__ __launch_bounds__(256) void relu_kernel(const float4* __restrict__ upd,
                                                   float4* __restrict__ out) {
    int i = blockIdx.x * blockDim.x + threadIdx.x;
    float4 c = upd[i];
    out[i] = make_float4(fmaxf(c.x, 0.f), fmaxf(c.y, 0.f),
                         fmaxf(c.z, 0.f), fmaxf(c.w, 0.f));
}

__device__ __forceinline__ float sample_plain(const float* __restrict__ img,
                                              int s, float dx, float dy,
                                              float bx, float by, float acc) {
    const float t  = fmaf((float)s, 1.f / (float)N_SAMPLES,
                          0.5f / (float)N_SAMPLES);
    const float px = fmaf(t, dx, bx);
    const float py = fmaf(t, dy, by);
    const float ix0f = floorf(px);
    const float iy0f = floorf(py);
    const float fx = px - ix0f;
    const float fy = py - iy0f;
    const int ix0 = (int)ix0f;
    const int iy0 = (int)iy0f;
    const float gx = ((unsigned)ix0       < (unsigned)IMG_W) ? (1.f - fx) : 0.f;
    const float hx = ((unsigned)(ix0 + 1) < (unsigned)IMG_W) ? fx         : 0.f;
    const float gy = ((unsigned)iy0       < (unsigned)IMG_H) ? (1.f - fy) : 0.f;
    const float hy = ((unsigned)(iy0 + 1) < (unsigned)IMG_H) ? fy         : 0.f;
    const unsigned cx0 = (unsigned)min(max(ix0, 0), IMG_W - 1);
    const unsigned cx1 = (unsigned)min(max(ix0 + 1, 0), IMG_W - 1);
    const unsigned r0  = (unsigned)min(max(iy0, 0), IMG_H - 1) << 9;
    const unsigned r1  = (unsigned)min(max(iy0 + 1, 0), IMG_H - 1) << 9;
    const float v00 = img[r0 + cx0];
    const float v01 = img[r0 + cx1];
    const float v10 = img[r1 + cx0];
    const float v11 = img[r1 + cx1];
    acc = fmaf(v00, gx * gy, acc);
    acc = fmaf(v01, hx * gy, acc);
    acc = fmaf(v10, gx * hy, acc);
    acc = fmaf(v11, hx * hy, acc);
    return acc;
}

__global__ __launch_bounds__(256) void fanproj_plain_kernel(
        const float* __restrict__ img,
        const float* __restrict__ src_pos,
        const float* __restrict__ det_center,
        const float* __restrict__ det_u,
        float* __restrict__ sino) {
    const int wid  = (blockIdx.x * blockDim.x + threadIdx.x) >> 6;
    const int lane = threadIdx.x & 63;
    if (wid >= N_RAYS) return;
    const int v   = wid >> 9;
    const int det = wid & 511;
    const float sx = src_pos[2 * v];
    const float sy = src_pos[2 * v + 1];
    const float u  = ((float)det - 255.5f) * 2.0f;
    const float ex = det_center[2 * v]     + u * det_u[2 * v];
    const float ey = det_center[2 * v + 1] + u * det_u[2 * v + 1];
    const float dx = ex - sx;
    const float dy = ey - sy;
    const float seg = sqrtf(dx * dx + dy * dy);
    const float bx = sx + 255.5f;
    const float by = sy + 255.5f;
    const float lo = -256.5f, hi = 256.5f;
    float t0 = 0.f, t1 = 1.f;
    if (fabsf(dx) > 1e-12f) {
        float ta = (lo - sx) / dx, tb = (hi - sx) / dx;
        t0 = fmaxf(t0, fminf(ta, tb));
        t1 = fminf(t1, fmaxf(ta, tb));
    } else if (sx <= lo || sx >= hi) {
        t1 = -1.f;
    }
    if (fabsf(dy) > 1e-12f) {
        float ta = (lo - sy) / dy, tb = (hi - sy) / dy;
        t0 = fmaxf(t0, fminf(ta, tb));
        t1 = fminf(t1, fmaxf(ta, tb));
    } else if (sy <= lo || sy >= hi) {
        t1 = -1.f;
    }
    int s0 = 0, s1 = -1;
    if (t1 >= t0) {
        s0 = max(0, (int)floorf(t0 * (float)N_SAMPLES - 0.5f) - 1);
        s1 = min(N_SAMPLES - 1, (int)ceilf(t1 * (float)N_SAMPLES - 0.5f) + 1);
    }
    float acc0 = 0.f, acc1 = 0.f;
    int s = s0 + lane;
    for (; s + 64 <= s1; s += 128) {
        acc0 = sample_plain(img, s,      dx, dy, bx, by, acc0);
        acc1 = sample_plain(img, s + 64, dx, dy, bx, by, acc1);
    }
    if (s <= s1) acc0 = sample_plain(img, s, dx, dy, bx, by, acc0);
    float acc = acc0 + acc1;
    #pragma unroll
    for (int off = 32; off >= 1; off >>= 1) acc += __shfl_xor(acc, off);
    if (lane == 0) sino[wid] = acc * seg * (1.0f / (float)N_SAMPLES);
}

// ---------------------------------------------------------------------------
extern "C" void kernel_launch(void* const* d_in, const int* in_sizes, int n_in,
                              void* d_out, int out_size, void* d_ws, size_t ws_size,
                              hipStream_t stream) {
    const float* x          = (const float*)d_in[0];
    const float* reco       = (const float*)d_in[1];
    const float* src_pos    = (const float*)d_in[2];
    const float* det_center = (const float*)d_in[3];
    const float* det_u      = (const float*)d_in[4];

    float* out  = (float*)d_out;
    float* sino = out;                 // [180*512]
    float* relu = out + N_RAYS;        // [512*512]

    const int n4 = IMG_N / 4;          // 65536

    if (ws_size >= Q_BYTES + RAYINFO_BYTES) {
        uint2*  Q  = (uint2*)d_ws;                        // ~2.24 MiB
        float4* RA = (float4*)((char*)d_ws + ((Q_BYTES + 255) & ~(size_t)255));
        float4* RB = RA + N_RAYS;
        pack_q_relu_kernel<<<(Q_N + 255) / 256, 256, 0, stream>>>(
            x, reco, Q, relu);
        ray_setup_kernel<<<N_RAYS / 256, 256, 0, stream>>>(
            src_pos, det_center, det_u, RA, RB, sino);
        fanproj_tile_kernel<<<dim3(N_RAYS / 64, K_CHUNKS), 256, 0, stream>>>(
            Q, RA, RB, sino);
    } else {
        // minimal fallback: upd lives in the relu output region
        float* upd = relu;
        add_kernel<<<n4 / 256, 256, 0, stream>>>(
            (const float4*)x, (const float4*)reco, (float4*)upd);
        fanproj_plain_kernel<<<N_RAYS / 4, 256, 0, stream>>>(
            upd, src_pos, det_center, det_u, sino);
        relu_kernel<<<n4 / 256, 256, 0, stream>>>(
            (const float4*)upd, (float4*)relu);
    }
}

// Round 8
// 36.811 us; speedup vs baseline: 1.7018x; 1.2024x over previous
//
#include <hip/hip_runtime.h>
#include <hip/hip_bf16.h>
#include <hip/hip_fp16.h>

// Problem constants (from reference)
#define IMG_H 512
#define IMG_W 512
#define N_VIEWS 180
#define N_DET 512
#define N_SAMPLES 512

#define N_RAYS (N_VIEWS * N_DET)          // 92160
#define IMG_N (IMG_H * IMG_W)             // 262144

// Row-pair fp16 grid, 8-px zero pad ring:
//   R[(iy+8)*QDIM + (ix+8)] = half2{ I[iy][ix], I[iy+1][ix] }   (4 bytes)
// for ix,iy in [-8, 520], I==0 outside [0,512)^2.
// A bilinear sample at cell (ix,iy) reads R[iy][ix] and R[iy][ix+1]:
// 8 contiguous bytes -> one dword-aligned dwordx2 load, all 4 taps.
// The slab clip widens the sample range by <= ~6.4 px beyond the box, so all
// touched cells lie inside the pad -> no clamping, taps exactly reproduce the
// reference's zero-outside gather.
#define QPAD 8
#define QDIM (IMG_W + 1 + 2 * QPAD)       // 529
#define R_N (QDIM * QDIM)                 // 279841
#define R_BYTES ((size_t)R_N * 4)         // ~1.07 MiB
#define R_BYTES_AL ((R_BYTES + 255) & ~(size_t)255)
#define RAYINFO_BYTES ((size_t)N_RAYS * 32)

#define K_CHUNKS 4
#define PACK_BLOCKS ((R_N + 255) / 256)   // 1094
#define SETUP_BLOCKS (N_RAYS / 256)       // 360

// ---------------------------------------------------------------------------
// k1 (merged prep):
//   blocks [0, PACK_BLOCKS): pack R (row-pair half2) from x+reco; also emit
//     relu(x+reco) (each image pixel owned by exactly one thread).
//   blocks [PACK_BLOCKS, +SETUP_BLOCKS): per-ray setup ->
//     RA[rid]={dx,dy,bx,by}, RB[rid]={segscl,s0,len,0}; zero sino[rid].
// ---------------------------------------------------------------------------
__global__ __launch_bounds__(256) void prep_kernel(
        const float* __restrict__ x, const float* __restrict__ r,
        unsigned* __restrict__ R, float* __restrict__ relu_out,
        const float* __restrict__ src_pos,
        const float* __restrict__ det_center,
        const float* __restrict__ det_u,
        float4* __restrict__ RA, float4* __restrict__ RB,
        float* __restrict__ sino) {
    const int b = blockIdx.x;
    if (b < PACK_BLOCKS) {
        int i = b * 256 + threadIdx.x;
        if (i >= R_N) return;
        int row = i / QDIM;
        int col = i - row * QDIM;
        int yy = row - QPAD;   // taps (yy, yy+1) at x = xx
        int xx = col - QPAD;
        float v0 = 0.f, v1 = 0.f;
        if ((unsigned)xx < (unsigned)IMG_W) {
            if ((unsigned)yy < (unsigned)IMG_H) {
                int idx = yy * IMG_W + xx;
                v0 = x[idx] + r[idx];
            }
            if ((unsigned)(yy + 1) < (unsigned)IMG_H) {
                int idx = (yy + 1) * IMG_W + xx;
                v1 = x[idx] + r[idx];
            }
        }
        __half2 h = __floats2half2_rn(v0, v1);
        R[i] = *reinterpret_cast<unsigned*>(&h);
        if ((unsigned)xx < (unsigned)IMG_W && (unsigned)yy < (unsigned)IMG_H)
            relu_out[yy * IMG_W + xx] = fmaxf(v0, 0.f);
        return;
    }

    // ---- ray setup part ----
    const int rid = (b - PACK_BLOCKS) * 256 + threadIdx.x;
    const int v   = rid >> 9;
    const int det = rid & 511;

    const float sx = src_pos[2 * v];
    const float sy = src_pos[2 * v + 1];
    const float u  = ((float)det - 255.5f) * 2.0f;   // DET_SPACING = 2
    const float ex = det_center[2 * v]     + u * det_u[2 * v];
    const float ey = det_center[2 * v + 1] + u * det_u[2 * v + 1];

    const float dx = ex - sx;
    const float dy = ey - sy;
    const float segscl = sqrtf(dx * dx + dy * dy) * (1.0f / (float)N_SAMPLES);

    // slab clip of t in [0,1] against world box (-256.5, 256.5)^2 (perf only;
    // widened range overshoots the box by <= 6.4 px < QPAD)
    const float lo = -256.5f, hi = 256.5f;
    float t0 = 0.f, t1 = 1.f;
    if (fabsf(dx) > 1e-12f) {
        float ta = (lo - sx) / dx, tb = (hi - sx) / dx;
        t0 = fmaxf(t0, fminf(ta, tb));
        t1 = fminf(t1, fmaxf(ta, tb));
    } else if (sx <= lo || sx >= hi) {
        t1 = -1.f;
    }
    if (fabsf(dy) > 1e-12f) {
        float ta = (lo - sy) / dy, tb = (hi - sy) / dy;
        t0 = fmaxf(t0, fminf(ta, tb));
        t1 = fminf(t1, fmaxf(ta, tb));
    } else if (sy <= lo || sy >= hi) {
        t1 = -1.f;
    }
    int s0 = 0, len = 0;
    if (t1 >= t0) {
        s0 = max(0, (int)floorf(t0 * (float)N_SAMPLES - 0.5f) - 1);
        int s1 = min(N_SAMPLES - 1, (int)ceilf(t1 * (float)N_SAMPLES - 0.5f) + 1);
        len = s1 - s0 + 1;
        if (len < 0) len = 0;
    }
    RA[rid] = make_float4(dx, dy, sx + 255.5f + (float)QPAD,
                                  sy + 255.5f + (float)QPAD);
    RB[rid] = make_float4(segscl, (float)s0, (float)len, 0.f);
    sino[rid] = 0.f;
}

// ---------------------------------------------------------------------------
// row-pair bilinear sample: ONE 8B (dword-aligned) load, no clamp, no mask.
// px,py in (0.6, 526.4) -> trunc == floor, indices in-bounds.
// ---------------------------------------------------------------------------
__device__ __forceinline__ float sample_h(const unsigned* __restrict__ R,
                                          float t, float dx, float dy,
                                          float bx, float by, float acc) {
    const float px = fmaf(t, dx, bx);
    const float py = fmaf(t, dy, by);
    const float ixf = truncf(px);
    const float iyf = truncf(py);
    const float fx = px - ixf;
    const float fy = py - iyf;
    const int lin = (int)iyf * QDIM + (int)ixf;

    uint2 qw;
    __builtin_memcpy(&qw, R + lin, 8);   // {v00,v10}, {v01,v11}
    const float2 fa = __half22float2(*reinterpret_cast<const __half2*>(&qw.x));
    const float2 fb = __half22float2(*reinterpret_cast<const __half2*>(&qw.y));

    const float gx = 1.f - fx;
    const float h0 = fmaf(fx, fb.x, gx * fa.x);   // top row lerp
    const float h1 = fmaf(fx, fb.y, gx * fa.y);   // bottom row lerp
    acc = fmaf(1.f - fy, h0, acc);
    acc = fmaf(fy, h1, acc);
    return acc;
}

// ---------------------------------------------------------------------------
// k2: fan-beam projection, 2D lane tiling (16 dets x 4 sample-offsets).
//   block = 256 threads = 64 dets; grid = (1440, K_CHUNKS).
//   Per-ray partial reduced via shfl_xor(16/32); lane soff==0 does one atomic.
// ---------------------------------------------------------------------------
__global__ __launch_bounds__(256) void fanproj_tile_kernel(
        const unsigned* __restrict__ R,
        const float4* __restrict__ RA, const float4* __restrict__ RB,
        float* __restrict__ sino) {
    const int tix  = threadIdx.x;
    const int lane = tix & 63;
    const int dsub = lane & 15;
    const int soff = lane >> 4;                       // 0..3
    const int rid  = blockIdx.x * 64 + ((tix >> 6) << 4) + dsub;
    const int chunk = blockIdx.y;

    const float4 a = RA[rid];
    const float4 b = RB[rid];
    const float dx = a.x, dy = a.y, bx = a.z, by = a.w;
    const int s0  = (int)b.y;
    const int len = (int)b.z;
    const int c0 = s0 + ((len * chunk) >> 2);
    const int c1 = s0 + ((len * (chunk + 1)) >> 2) - 1;

    int s = c0 + soff;
    float t = ((float)s + 0.5f) * (1.0f / (float)N_SAMPLES);  // exact
    float acc0 = 0.f, acc1 = 0.f;
    for (; s + 4 <= c1; s += 8) {
        acc0 = sample_h(R, t,               dx, dy, bx, by, acc0);
        acc1 = sample_h(R, t + 0.0078125f,  dx, dy, bx, by, acc1); // +4/512
        t += 0.015625f;                                            // +8/512
    }
    if (s <= c1) acc0 = sample_h(R, t, dx, dy, bx, by, acc0);

    float acc = acc0 + acc1;
    acc += __shfl_xor(acc, 16);   // sum over the 4 sample-offset groups
    acc += __shfl_xor(acc, 32);
    if (soff == 0) {
        const float res = acc * b.x;
        if (res != 0.f) atomicAdd(&sino[rid], res);
    }
}

// ---------------------------------------------------------------------------
// Minimal fallback path (tiny workspace): plain projector straight from upd.
// ---------------------------------------------------------------------------
__global__ __launch_bounds__(256) void add_kernel(const float4* __restrict__ x,
                                                  const float4* __restrict__ r,
                                                  float4* __restrict__ upd) {
    int i = blockIdx.x * blockDim.x + threadIdx.x;
    float4 a = x[i];
    float4 b = r[i];
    upd[i] = make_float4(a.x + b.x, a.y + b.y, a.z + b.z, a.w + b.w);
}
__global__ __launch_bounds__(256) void relu_kernel(const float4* __restrict__ upd,
                                                   float4* __restrict__ out) {
    int i = blockIdx.x * blockDim.x + threadIdx.x;
    float4 c = upd[i];
    out[i] = make_float4(fmaxf(c.x, 0.f), fmaxf(c.y, 0.f),
                         fmaxf(c.z, 0.f), fmaxf(c.w, 0.f));
}

__device__ __forceinline__ float sample_plain(const float* __restrict__ img,
                                              int s, float dx, float dy,
                                              float bx, float by, float acc) {
    const float t  = fmaf((float)s, 1.f / (float)N_SAMPLES,
                          0.5f / (float)N_SAMPLES);
    const float px = fmaf(t, dx, bx);
    const float py = fmaf(t, dy, by);
    const float ix0f = floorf(px);
    const float iy0f = floorf(py);
    const float fx = px - ix0f;
    const float fy = py - iy0f;
    const int ix0 = (int)ix0f;
    const int iy0 = (int)iy0f;
    const float gx = ((unsigned)ix0       < (unsigned)IMG_W) ? (1.f - fx) : 0.f;
    const float hx = ((unsigned)(ix0 + 1) < (unsigned)IMG_W) ? fx         : 0.f;
    const float gy = ((unsigned)iy0       < (unsigned)IMG_H) ? (1.f - fy) : 0.f;
    const float hy = ((unsigned)(iy0 + 1) < (unsigned)IMG_H) ? fy         : 0.f;
    const unsigned cx0 = (unsigned)min(max(ix0, 0), IMG_W - 1);
    const unsigned cx1 = (unsigned)min(max(ix0 + 1, 0), IMG_W - 1);
    const unsigned r0  = (unsigned)min(max(iy0, 0), IMG_H - 1) << 9;
    const unsigned r1  = (unsigned)min(max(iy0 + 1, 0), IMG_H - 1) << 9;
    const float v00 = img[r0 + cx0];
    const float v01 = img[r0 + cx1];
    const float v10 = img[r1 + cx0];
    const float v11 = img[r1 + cx1];
    acc = fmaf(v00, gx * gy, acc);
    acc = fmaf(v01, hx * gy, acc);
    acc = fmaf(v10, gx * hy, acc);
    acc = fmaf(v11, hx * hy, acc);
    return acc;
}

__global__ __launch_bounds__(256) void fanproj_plain_kernel(
        const float* __restrict__ img,
        const float* __restrict__ src_pos,
        const float* __restrict__ det_center,
        const float* __restrict__ det_u,
        float* __restrict__ sino) {
    const int wid  = (blockIdx.x * blockDim.x + threadIdx.x) >> 6;
    const int lane = threadIdx.x & 63;
    if (wid >= N_RAYS) return;
    const int v   = wid >> 9;
    const int det = wid & 511;
    const float sx = src_pos[2 * v];
    const float sy = src_pos[2 * v + 1];
    const float u  = ((float)det - 255.5f) * 2.0f;
    const float ex = det_center[2 * v]     + u * det_u[2 * v];
    const float ey = det_center[2 * v + 1] + u * det_u[2 * v + 1];
    const float dx = ex - sx;
    const float dy = ey - sy;
    const float seg = sqrtf(dx * dx + dy * dy);
    const float bx = sx + 255.5f;
    const float by = sy + 255.5f;
    const float lo = -256.5f, hi = 256.5f;
    float t0 = 0.f, t1 = 1.f;
    if (fabsf(dx) > 1e-12f) {
        float ta = (lo - sx) / dx, tb = (hi - sx) / dx;
        t0 = fmaxf(t0, fminf(ta, tb));
        t1 = fminf(t1, fmaxf(ta, tb));
    } else if (sx <= lo || sx >= hi) {
        t1 = -1.f;
    }
    if (fabsf(dy) > 1e-12f) {
        float ta = (lo - sy) / dy, tb = (hi - sy) / dy;
        t0 = fmaxf(t0, fminf(ta, tb));
        t1 = fminf(t1, fmaxf(ta, tb));
    } else if (sy <= lo || sy >= hi) {
        t1 = -1.f;
    }
    int s0 = 0, s1 = -1;
    if (t1 >= t0) {
        s0 = max(0, (int)floorf(t0 * (float)N_SAMPLES - 0.5f) - 1);
        s1 = min(N_SAMPLES - 1, (int)ceilf(t1 * (float)N_SAMPLES - 0.5f) + 1);
    }
    float acc0 = 0.f, acc1 = 0.f;
    int s = s0 + lane;
    for (; s + 64 <= s1; s += 128) {
        acc0 = sample_plain(img, s,      dx, dy, bx, by, acc0);
        acc1 = sample_plain(img, s + 64, dx, dy, bx, by, acc1);
    }
    if (s <= s1) acc0 = sample_plain(img, s, dx, dy, bx, by, acc0);
    float acc = acc0 + acc1;
    #pragma unroll
    for (int off = 32; off >= 1; off >>= 1) acc += __shfl_xor(acc, off);
    if (lane == 0) sino[wid] = acc * seg * (1.0f / (float)N_SAMPLES);
}

// ---------------------------------------------------------------------------
extern "C" void kernel_launch(void* const* d_in, const int* in_sizes, int n_in,
                              void* d_out, int out_size, void* d_ws, size_t ws_size,
                              hipStream_t stream) {
    const float* x          = (const float*)d_in[0];
    const float* reco       = (const float*)d_in[1];
    const float* src_pos    = (const float*)d_in[2];
    const float* det_center = (const float*)d_in[3];
    const float* det_u      = (const float*)d_in[4];

    float* out  = (float*)d_out;
    float* sino = out;                 // [180*512]
    float* relu = out + N_RAYS;        // [512*512]

    const int n4 = IMG_N / 4;          // 65536

    if (ws_size >= R_BYTES_AL + RAYINFO_BYTES) {
        unsigned* R  = (unsigned*)d_ws;                        // ~1.07 MiB
        float4*   RA = (float4*)((char*)d_ws + R_BYTES_AL);
        float4*   RB = RA + N_RAYS;
        prep_kernel<<<PACK_BLOCKS + SETUP_BLOCKS, 256, 0, stream>>>(
            x, reco, R, relu, src_pos, det_center, det_u, RA, RB, sino);
        fanproj_tile_kernel<<<dim3(N_RAYS / 64, K_CHUNKS), 256, 0, stream>>>(
            R, RA, RB, sino);
    } else {
        // minimal fallback: upd lives in the relu output region
        float* upd = relu;
        add_kernel<<<n4 / 256, 256, 0, stream>>>(
            (const float4*)x, (const float4*)reco, (float4*)upd);
        fanproj_plain_kernel<<<N_RAYS / 4, 256, 0, stream>>>(
            upd, src_pos, det_center, det_u, sino);
        relu_kernel<<<n4 / 256, 256, 0, stream>>>(
            (const float4*)upd, (float4*)relu);
    }
}